// Round 1
// baseline (190.785 us; speedup 1.0000x reference)
//
#include <hip/hip_runtime.h>

// Problem constants
#define B_    16
#define N_    1024
#define DIN_  256
#define H_    4
#define F_    64
#define COUT_ 256
#define NEG_  0.2f

typedef __bf16 bf16x8 __attribute__((ext_vector_type(8)));
typedef float  f32x4  __attribute__((ext_vector_type(4)));
typedef unsigned short u16x8 __attribute__((ext_vector_type(8)));
typedef unsigned short u16x4 __attribute__((ext_vector_type(4)));

__device__ __forceinline__ unsigned short f2bf(float f) {
    unsigned u = __builtin_bit_cast(unsigned, f);
    u += 0x7fffu + ((u >> 16) & 1u);
    return (unsigned short)(u >> 16);
}

// ---------------------------------------------------------------------------
// Kernel 0: transpose W [DIN][H*F] -> Wt bf16 [H*F][DIN] (B-operand layout:
// per-lane 8 consecutive k for a fixed output column).
// ---------------------------------------------------------------------------
__global__ __launch_bounds__(256) void wt_kernel(const float* __restrict__ W,
                                                 unsigned short* __restrict__ Wt) {
    int c = blockIdx.x;      // output column (h*F+f), 0..255
    int d = threadIdx.x;     // input dim, 0..255
    Wt[c * DIN_ + d] = f2bf(W[d * COUT_ + c]);
}

// ---------------------------------------------------------------------------
// Kernel A: h = x @ W via bf16 MFMA; store h_t bf16 [B][H][F][N] (transposed
// so kernel C's B-frags are contiguous 16B loads); also e_src/e_dst logits
// reduced in the epilogue (wave w == head w, F=64 == wave width).
// Block = 256 thr (4 waves), grid = B * (N/32): 32-row i-tile per block.
// ---------------------------------------------------------------------------
__global__ __launch_bounds__(256, 2) void gat_h_kernel(
    const float* __restrict__ x, const float* __restrict__ a_src,
    const float* __restrict__ a_dst, const unsigned short* __restrict__ Wt,
    unsigned short* __restrict__ h_t, float* __restrict__ e_src,
    float* __restrict__ e_dst) {
    const int b   = blockIdx.x >> 5;
    const int it0 = (blockIdx.x & 31) * 32;
    const int w   = threadIdx.x >> 6;   // wave id == head
    const int ln  = threadIdx.x & 63;
    const int l15 = ln & 15;
    const int q   = ln >> 4;

    f32x4 acc[2][4];
#pragma unroll
    for (int mt = 0; mt < 2; mt++)
#pragma unroll
        for (int ft = 0; ft < 4; ft++) acc[mt][ft] = (f32x4)0.0f;

#pragma unroll
    for (int k0 = 0; k0 < DIN_; k0 += 32) {
        const int kb = k0 + q * 8;
        bf16x8 af[2];
#pragma unroll
        for (int mt = 0; mt < 2; mt++) {
            const int i = it0 + mt * 16 + l15;
            const f32x4* xp = (const f32x4*)(x + (b * N_ + i) * DIN_ + kb);
            f32x4 xa = xp[0], xb = xp[1];
            u16x8 u;
            u[0] = f2bf(xa[0]); u[1] = f2bf(xa[1]); u[2] = f2bf(xa[2]); u[3] = f2bf(xa[3]);
            u[4] = f2bf(xb[0]); u[5] = f2bf(xb[1]); u[6] = f2bf(xb[2]); u[7] = f2bf(xb[3]);
            af[mt] = __builtin_bit_cast(bf16x8, u);
        }
#pragma unroll
        for (int ft = 0; ft < 4; ft++) {
            const int c = w * 64 + ft * 16 + l15;
            bf16x8 bf = *((const bf16x8*)(Wt + c * DIN_ + kb));
#pragma unroll
            for (int mt = 0; mt < 2; mt++)
                acc[mt][ft] = __builtin_amdgcn_mfma_f32_16x16x32_bf16(af[mt], bf, acc[mt][ft], 0, 0, 0);
        }
    }

    // Epilogue: store h_t (bf16), reduce e_src/e_dst over f.
    float as_v[4], ad_v[4];
#pragma unroll
    for (int ft = 0; ft < 4; ft++) {
        as_v[ft] = a_src[w * 64 + ft * 16 + l15];
        ad_v[ft] = a_dst[w * 64 + ft * 16 + l15];
    }
    float ps[2][4], pd[2][4];
#pragma unroll
    for (int mt = 0; mt < 2; mt++)
#pragma unroll
        for (int r = 0; r < 4; r++) { ps[mt][r] = 0.0f; pd[mt][r] = 0.0f; }

#pragma unroll
    for (int mt = 0; mt < 2; mt++) {
#pragma unroll
        for (int ft = 0; ft < 4; ft++) {
            u16x4 hb;
#pragma unroll
            for (int r = 0; r < 4; r++) {
                float hv = acc[mt][ft][r];   // D row = q*4+r, col = ft*16+l15
                hb[r] = f2bf(hv);
                ps[mt][r] += hv * as_v[ft];
                pd[mt][r] += hv * ad_v[ft];
            }
            const int f    = ft * 16 + l15;
            const int addr = ((b * H_ + w) * F_ + f) * N_ + it0 + mt * 16 + q * 4;
            *((u16x4*)(h_t + addr)) = hb;
        }
    }
    // Reduce over the 16-lane (f mod 16) groups; ft already summed in-register.
#pragma unroll
    for (int mt = 0; mt < 2; mt++)
#pragma unroll
        for (int r = 0; r < 4; r++) {
            float vs = ps[mt][r], vd = pd[mt][r];
            vs += __shfl_xor(vs, 1); vs += __shfl_xor(vs, 2);
            vs += __shfl_xor(vs, 4); vs += __shfl_xor(vs, 8);
            vd += __shfl_xor(vd, 1); vd += __shfl_xor(vd, 2);
            vd += __shfl_xor(vd, 4); vd += __shfl_xor(vd, 8);
            if (l15 == 0) {
                const int i = it0 + mt * 16 + q * 4 + r;
                e_src[(b * H_ + w) * N_ + i] = vs;
                e_dst[(b * H_ + w) * N_ + i] = vd;
            }
        }
}

// ---------------------------------------------------------------------------
// Kernel C: fused mask/leaky/exp + (P @ h) MFMA + normalize + bias.
// No max-subtraction needed: logits are O(few), exp() safe, and masked
// entries are exactly 0 (matching exp(-1e9 - m) == 0 in the reference).
// Row sums accumulated alongside (from bf16-rounded p for consistency).
// Block = 256 thr (wave w = head w), grid = B * (N/32).
// ---------------------------------------------------------------------------
__global__ __launch_bounds__(256, 2) void gat_attn_kernel(
    const float* __restrict__ adj, const unsigned short* __restrict__ h_t,
    const float* __restrict__ e_src, const float* __restrict__ e_dst,
    const float* __restrict__ bias, float* __restrict__ out) {
    const int b   = blockIdx.x >> 5;
    const int it0 = (blockIdx.x & 31) * 32;
    const int w   = threadIdx.x >> 6;
    const int ln  = threadIdx.x & 63;
    const int l15 = ln & 15;
    const int q   = ln >> 4;

    float edv[2];
#pragma unroll
    for (int mt = 0; mt < 2; mt++)
        edv[mt] = e_dst[(b * H_ + w) * N_ + it0 + mt * 16 + l15];
    float bias_v[4];
#pragma unroll
    for (int ft = 0; ft < 4; ft++) bias_v[ft] = bias[w * 64 + ft * 16 + l15];

    f32x4 acc[2][4];
#pragma unroll
    for (int mt = 0; mt < 2; mt++)
#pragma unroll
        for (int ft = 0; ft < 4; ft++) acc[mt][ft] = (f32x4)0.0f;
    float rs[2] = {0.0f, 0.0f};

    const float* es_base          = e_src + (b * H_ + w) * N_;
    const unsigned short* hb_base = h_t + (b * H_ + w) * F_ * N_;

    for (int j0 = 0; j0 < N_; j0 += 32) {
        const int jb = j0 + q * 8;
        const f32x4* esp = (const f32x4*)(es_base + jb);
        f32x4 es0 = esp[0], es1 = esp[1];
        float es[8] = {es0[0], es0[1], es0[2], es0[3], es1[0], es1[1], es1[2], es1[3]};

        bf16x8 bfr[4];
#pragma unroll
        for (int ft = 0; ft < 4; ft++)
            bfr[ft] = *((const bf16x8*)(hb_base + (ft * 16 + l15) * N_ + jb));

        bf16x8 afr[2];
#pragma unroll
        for (int mt = 0; mt < 2; mt++) {
            const int i = it0 + mt * 16 + l15;
            const f32x4* ap = (const f32x4*)(adj + (b * N_ + i) * N_ + jb);
            f32x4 aa = ap[0], ab = ap[1];
            float av[8] = {aa[0], aa[1], aa[2], aa[3], ab[0], ab[1], ab[2], ab[3]};
            u16x8 u;
            float rloc = 0.0f;
#pragma unroll
            for (int jj = 0; jj < 8; jj++) {
                float t = edv[mt] + es[jj];
                t = fmaxf(t, 0.0f) + NEG_ * fminf(t, 0.0f);   // leaky_relu
                float pe = __expf(t);
                float pv = (av[jj] > 0.5f) ? pe : 0.0f;
                unsigned ub = __builtin_bit_cast(unsigned, pv);
                ub = (ub + 0x7fffu + ((ub >> 16) & 1u)) & 0xffff0000u;  // RTNE to bf16
                rloc += __builtin_bit_cast(float, ub);
                u[jj] = (unsigned short)(ub >> 16);
            }
            rs[mt] += rloc;
            afr[mt] = __builtin_bit_cast(bf16x8, u);
        }
#pragma unroll
        for (int mt = 0; mt < 2; mt++)
#pragma unroll
            for (int ft = 0; ft < 4; ft++)
                acc[mt][ft] = __builtin_amdgcn_mfma_f32_16x16x32_bf16(afr[mt], bfr[ft], acc[mt][ft], 0, 0, 0);
    }

    // Row-sum: partials per quad -> full sums at every lane (for i = mt*16+l15).
#pragma unroll
    for (int mt = 0; mt < 2; mt++) {
        rs[mt] += __shfl_xor(rs[mt], 16);
        rs[mt] += __shfl_xor(rs[mt], 32);
    }
    // Epilogue needs sums for D rows i = mt*16 + q*4 + r -> pull from lane q*4+r.
    float rinv[2][4];
#pragma unroll
    for (int mt = 0; mt < 2; mt++)
#pragma unroll
        for (int r = 0; r < 4; r++) {
            float v = __shfl(rs[mt], q * 4 + r);
            rinv[mt][r] = 1.0f / v;
        }
#pragma unroll
    for (int mt = 0; mt < 2; mt++)
#pragma unroll
        for (int ft = 0; ft < 4; ft++)
#pragma unroll
            for (int r = 0; r < 4; r++) {
                const int i = it0 + mt * 16 + q * 4 + r;
                const int c = w * 64 + ft * 16 + l15;
                out[(b * N_ + i) * COUT_ + c] = acc[mt][ft][r] * rinv[mt][r] + bias_v[ft];
            }
}

// ---------------------------------------------------------------------------
// Workspace layout (bytes):
//   [0, 128K)              Wt   bf16 [256][256]
//   [128K, 128K+8M)        h_t  bf16 [B][H][F][N]
//   [+8M, +8M+256K)        e_src f32 [B][H][N]
//   [+256K, +512K)         e_dst f32 [B][H][N]
// Total ~9 MB.
// ---------------------------------------------------------------------------
extern "C" void kernel_launch(void* const* d_in, const int* in_sizes, int n_in,
                              void* d_out, int out_size, void* d_ws, size_t ws_size,
                              hipStream_t stream) {
    const float* x     = (const float*)d_in[0];
    const float* adj   = (const float*)d_in[1];
    const float* W     = (const float*)d_in[2];
    const float* a_src = (const float*)d_in[3];
    const float* a_dst = (const float*)d_in[4];
    const float* bias  = (const float*)d_in[5];
    float* out = (float*)d_out;

    char* ws = (char*)d_ws;
    unsigned short* Wt  = (unsigned short*)ws;
    unsigned short* h_t = (unsigned short*)(ws + (131072));
    float* e_src = (float*)(ws + 131072 + 8388608);
    float* e_dst = (float*)(ws + 131072 + 8388608 + 262144);

    wt_kernel<<<256, 256, 0, stream>>>(W, Wt);
    gat_h_kernel<<<B_ * (N_ / 32), 256, 0, stream>>>(x, a_src, a_dst, Wt, h_t, e_src, e_dst);
    gat_attn_kernel<<<B_ * (N_ / 32), 256, 0, stream>>>(adj, h_t, e_src, e_dst, bias, out);
}